// Round 13
// baseline (399.989 us; speedup 1.0000x reference)
//
#include <hip/hip_runtime.h>
#include <hip/hip_bf16.h>

#define EPSF 1e-5f

typedef __bf16 bf16x8 __attribute__((ext_vector_type(8)));
typedef float f32x4 __attribute__((ext_vector_type(4)));
typedef short svec8 __attribute__((ext_vector_type(8)));
typedef short svec4 __attribute__((ext_vector_type(4)));

__device__ __forceinline__ float bf2f(unsigned short h) {
  unsigned int u = ((unsigned int)h) << 16;
  return __builtin_bit_cast(float, u);
}
__device__ __forceinline__ unsigned short f2bf(float f) {
  unsigned int u = __builtin_bit_cast(unsigned int, f);
  unsigned int r = (u + 0x7fffu + ((u >> 16) & 1u)) >> 16;
  return (unsigned short)r;
}
// dual-mode scalar read: f32 (mode=1) or bf16 (mode=0)
__device__ __forceinline__ float ldx(const void* p, size_t i, int f32m) {
  return f32m ? ((const float*)p)[i] : bf2f(((const unsigned short*)p)[i]);
}
// dual-mode 8-element load -> 8 bf16 (svec8)
__device__ __forceinline__ svec8 ld8bf(const void* p, size_t eoff, int f32m) {
  if (!f32m) {
    uint4 u = *(const uint4*)((const unsigned short*)p + eoff);
    return __builtin_bit_cast(svec8, u);
  }
  const float* q = (const float*)p + eoff;
  float4 a = ((const float4*)q)[0];
  float4 b = ((const float4*)q)[1];
  svec8 r;
  r[0] = (short)f2bf(a.x); r[1] = (short)f2bf(a.y);
  r[2] = (short)f2bf(a.z); r[3] = (short)f2bf(a.w);
  r[4] = (short)f2bf(b.x); r[5] = (short)f2bf(b.y);
  r[6] = (short)f2bf(b.z); r[7] = (short)f2bf(b.w);
  return r;
}
// async global->LDS, 16 bytes per lane (dest must be wave-uniform base + lane*16)
__device__ __forceinline__ void gload16(const void* g, void* l) {
  __builtin_amdgcn_global_load_lds(
      (const __attribute__((address_space(1))) unsigned int*)g,
      (__attribute__((address_space(3))) unsigned int*)l, 16, 0, 0);
}
// fast silu: y * 1/(1+e^-y) via native exp (err ~1e-6 << bf16 rounding)
__device__ __forceinline__ float fsilu(float y) {
  return y * __builtin_amdgcn_rcpf(1.f + __expf(-y));
}
// fast tanh: 1 - 2/(e^{2y}+1); exact limits at +/-inf
__device__ __forceinline__ float ftanh(float y) {
  return 1.f - 2.f * __builtin_amdgcn_rcpf(__expf(2.f * y) + 1.f);
}

// block-wide (256 thr) sum of (x,y) via wave shuffles; s = float[16] scratch
__device__ __forceinline__ float2 bred2(float x, float y, float* s) {
#pragma unroll
  for (int o = 32; o > 0; o >>= 1) {
    x += __shfl_xor(x, o, 64);
    y += __shfl_xor(y, o, 64);
  }
  int w = threadIdx.x >> 6;
  if ((threadIdx.x & 63) == 0) { s[w] = x; s[8 + w] = y; }
  __syncthreads();
  float rx = s[0] + s[1] + s[2] + s[3];
  float ry = s[8] + s[9] + s[10] + s[11];
  __syncthreads();
  return make_float2(rx, ry);
}

// ---- probes: flags[0]=1 if float inputs are f32; flags[1]=1 if cat is int64
__global__ void detect_mode(const unsigned short* rgb, const int* cat, int* flags) {
  __shared__ int c1s, c2s;
  if (threadIdx.x == 0) { c1s = 0; c2s = 0; }
  __syncthreads();
  int c1 = 0, c2 = 0;
  for (int i = threadIdx.x; i < 4096; i += 256) {
    unsigned e = (rgb[i] >> 7) & 0xFFu;
    if (e >= 0x90u) c1++;
  }
  for (int i = threadIdx.x; i < 1024; i += 256) {
    if (cat[2 * i + 1] != 0) c2++;
  }
  atomicAdd(&c1s, c1);
  atomicAdd(&c2s, c2);
  __syncthreads();
  if (threadIdx.x == 0) {
    flags[0] = (c1s > 64) ? 1 : 0;
    flags[1] = (c2s < 8) ? 1 : 0;
  }
}

// ---- zero an f32 buffer (graph-safe, re-run every launch) -------------------
__global__ void zerof(float* p, int n4) {
  int i = blockIdx.x * 256 + threadIdx.x;
  if (i < n4) ((float4*)p)[i] = make_float4(0.f, 0.f, 0.f, 0.f);
}

// -------- MFMA GEMM, natural-layout B (rgb path; R11-measured 92 us) ---------
// (R12's BsT column-staged variant regressed: (row*40+q*8) b128 pattern is an
// 8-deep bank-alias class -> conflicts 6.3M->7.3M, +VALU addressing. Reverted.)
__global__ __launch_bounds__(256) void gemm64m(
    const void* __restrict__ A, int lda,
    const void* __restrict__ B0, const void* __restrict__ B1,
    int ldbn, int nsplit,
    void* __restrict__ Cv, int ldc, int kslice,
    const int* __restrict__ flags, int aDyn, int outKind) {
  __shared__ __align__(16) unsigned short As[64 * 40];
  __shared__ __align__(16) unsigned short Bs[32 * 68];
  int t = threadIdx.x;
  int mode = flags[0], am = aDyn ? mode : 0;
  int wave = t >> 6, lane = t & 63, mr = lane & 15, q = lane >> 4;
  int m0 = blockIdx.x * 64, n0 = blockIdx.y * 64;
  int kbeg = blockIdx.z * kslice;
  const void* B = B0; int nb = n0;
  if (n0 >= nsplit) { B = B1; nb = n0 - nsplit; }
  int arow = t >> 2, acol = (t & 3) * 8;   // A-tile 64m x 32k
  int brow = t >> 3, bcol = (t & 7) * 8;   // B-tile 32k x 64n
  size_t abase = (size_t)(m0 + arow) * lda + kbeg + acol;
  size_t bbase = (size_t)(kbeg + brow) * ldbn + nb + bcol;
  f32x4 acc[4];
#pragma unroll
  for (int i = 0; i < 4; i++) acc[i] = (f32x4){0.f, 0.f, 0.f, 0.f};
  svec8 ra = ld8bf(A, abase, am);
  svec8 rb = ld8bf(B, bbase, mode);
  int aw = arow * 40 + acol;
  int bw = brow * 68 + bcol;
  for (int k0 = 0; k0 < kslice; k0 += 32) {
    *(svec8*)&As[aw] = ra;
    *(svec4*)&Bs[bw]     = __builtin_shufflevector(rb, rb, 0, 1, 2, 3);
    *(svec4*)&Bs[bw + 4] = __builtin_shufflevector(rb, rb, 4, 5, 6, 7);
    __syncthreads();
    if (k0 + 32 < kslice) {  // register prefetch of next K-tile
      ra = ld8bf(A, abase + k0 + 32, am);
      rb = ld8bf(B, bbase + (size_t)(k0 + 32) * ldbn, mode);
    }
    svec8 bsv;
#pragma unroll
    for (int j = 0; j < 8; j++)
      bsv[j] = (short)Bs[(q * 8 + j) * 68 + wave * 16 + mr];
    bf16x8 bfr = __builtin_bit_cast(bf16x8, bsv);
#pragma unroll
    for (int i = 0; i < 4; i++) {
      bf16x8 afr = *(const bf16x8*)(const void*)&As[(i * 16 + mr) * 40 + q * 8];
      acc[i] = __builtin_amdgcn_mfma_f32_16x16x32_bf16(afr, bfr, acc[i], 0, 0, 0);
    }
    __syncthreads();
  }
  int n = n0 + wave * 16 + mr;
  if (outKind == 2) {
    unsigned short* C = (unsigned short*)Cv;
#pragma unroll
    for (int i = 0; i < 4; i++)
#pragma unroll
      for (int r = 0; r < 4; r++)
        C[(size_t)(m0 + i * 16 + q * 4 + r) * ldc + n] = f2bf(acc[i][r]);
  } else if (outKind == 0) {
    float* C = (float*)Cv;
#pragma unroll
    for (int i = 0; i < 4; i++)
#pragma unroll
      for (int r = 0; r < 4; r++)
        C[(size_t)(m0 + i * 16 + q * 4 + r) * ldc + n] = acc[i][r];
  } else {
    float* C = (float*)Cv;
#pragma unroll
    for (int i = 0; i < 4; i++)
#pragma unroll
      for (int r = 0; r < 4; r++)
        atomicAdd(&C[(size_t)(m0 + i * 16 + q * 4 + r) * ldc + n], acc[i][r]);
  }
}

// -------- LDS-free GEMM: C[2048,512] f32 = A[2048,512]bf16 @ BT[512,512]^T ---
// grid (32, 16): block = 4 independent waves, wave = 16 rows x 32 cols.
__global__ __launch_bounds__(256) void gemm_abt(
    const unsigned short* __restrict__ A, const unsigned short* __restrict__ BT,
    float* __restrict__ C) {
  int t = threadIdx.x;
  int w = t >> 6, l = t & 63, l15 = l & 15, l4 = l >> 4;
  int r0 = (blockIdx.x * 4 + w) * 16;
  int c0 = blockIdx.y * 32;
  f32x4 acc0 = (f32x4){0.f, 0.f, 0.f, 0.f}, acc1 = acc0;
  const unsigned short* Ap  = A  + (size_t)(r0 + l15) * 512 + l4 * 8;
  const unsigned short* Bp0 = BT + (size_t)(c0 + l15) * 512 + l4 * 8;
  const unsigned short* Bp1 = Bp0 + 16 * 512;
#pragma unroll 4
  for (int k0 = 0; k0 < 512; k0 += 32) {
    bf16x8 af = *(const bf16x8*)(const void*)(Ap + k0);
    bf16x8 b0 = *(const bf16x8*)(const void*)(Bp0 + k0);
    bf16x8 b1 = *(const bf16x8*)(const void*)(Bp1 + k0);
    acc0 = __builtin_amdgcn_mfma_f32_16x16x32_bf16(af, b0, acc0, 0, 0, 0);
    acc1 = __builtin_amdgcn_mfma_f32_16x16x32_bf16(af, b1, acc1, 0, 0, 0);
  }
#pragma unroll
  for (int rr = 0; rr < 4; rr++) {
    C[(size_t)(r0 + l4 * 4 + rr) * 512 + c0 + l15] = acc0[rr];
    C[(size_t)(r0 + l4 * 4 + rr) * 512 + c0 + 16 + l15] = acc1[rr];
  }
}

// --------- heads: LN(rgb GEMM halves)+tanh + tiny low-obs path ---------------
__global__ __launch_bounds__(256) void ln_heads(
    const float* __restrict__ CF, const void* __restrict__ low,
    const void* __restrict__ vWlow, const void* __restrict__ qWlow,
    const void* __restrict__ vgr, const void* __restrict__ vbr,
    const void* __restrict__ qgr, const void* __restrict__ qbr,
    const void* __restrict__ vgl, const void* __restrict__ vbl,
    const void* __restrict__ qgl, const void* __restrict__ qbl,
    unsigned short* __restrict__ hv, unsigned short* __restrict__ hq,
    const int* __restrict__ flags) {
  __shared__ float lowf[32];
  __shared__ float red[16];
  int mode = flags[0];
  int b = blockIdx.x, j = threadIdx.x;
  if (j < 32) lowf[j] = ldx(low, (size_t)b * 32 + j, mode);
  __syncthreads();
  float xvr = CF[(size_t)b * 512 + j];
  float xqr = CF[(size_t)b * 512 + 256 + j];
  float xvl = 0.f, xql = 0.f;
#pragma unroll 4
  for (int k = 0; k < 32; k++) {
    float l = lowf[k];
    xvl += l * ldx(vWlow, k * 256 + j, mode);
    xql += l * ldx(qWlow, k * 256 + j, mode);
  }
  float2 r;
  r = bred2(xvr, xvr * xvr, red);
  {
    float mu = r.x * (1.f / 256.f), var = r.y * (1.f / 256.f) - mu * mu;
    float y = (xvr - mu) * rsqrtf(fmaxf(var, 0.f) + EPSF) * ldx(vgr, j, mode) + ldx(vbr, j, mode);
    hv[(size_t)b * 512 + j] = f2bf(ftanh(y));
  }
  r = bred2(xvl, xvl * xvl, red);
  {
    float mu = r.x * (1.f / 256.f), var = r.y * (1.f / 256.f) - mu * mu;
    float y = (xvl - mu) * rsqrtf(fmaxf(var, 0.f) + EPSF) * ldx(vgl, j, mode) + ldx(vbl, j, mode);
    hv[(size_t)b * 512 + 256 + j] = f2bf(ftanh(y));
  }
  r = bred2(xqr, xqr * xqr, red);
  {
    float mu = r.x * (1.f / 256.f), var = r.y * (1.f / 256.f) - mu * mu;
    float y = (xqr - mu) * rsqrtf(fmaxf(var, 0.f) + EPSF) * ldx(qgr, j, mode) + ldx(qbr, j, mode);
    hq[(size_t)b * 512 + j] = f2bf(ftanh(y));
  }
  r = bred2(xql, xql * xql, red);
  {
    float mu = r.x * (1.f / 256.f), var = r.y * (1.f / 256.f) - mu * mu;
    float y = (xql - mu) * rsqrtf(fmaxf(var, 0.f) + EPSF) * ldx(qgl, j, mode) + ldx(qbl, j, mode);
    hq[(size_t)b * 512 + 256 + j] = f2bf(ftanh(y));
  }
}

// ---------- transpose natural [K][N] (f32 or bf16) -> bf16 out[N][K] ---------
__global__ __launch_bounds__(256) void tr_bf16(
    const void* __restrict__ in, int K, int N,
    unsigned short* __restrict__ out, const int* __restrict__ flags) {
  __shared__ float tile[32][33];
  int mode = flags[0];
  int k0 = blockIdx.x * 32, n0 = blockIdx.y * 32;
  int t = threadIdx.x, ty = t >> 5, tx = t & 31;
#pragma unroll
  for (int i = 0; i < 4; i++)
    tile[ty + i * 8][tx] = ldx(in, (size_t)(k0 + ty + i * 8) * N + n0 + tx, mode);
  __syncthreads();
#pragma unroll
  for (int i = 0; i < 4; i++)
    out[(size_t)(n0 + ty + i * 8) * K + k0 + tx] = f2bf(tile[tx][ty + i * 8]);
}

// ---- shared LN/GEMM building blocks (q_tail-verified), 1024 thr 4Mx4N -------
#define LNSTATS1(ACC)                                                         \
  {                                                                           \
    _Pragma("unroll") for (int rr = 0; rr < 4; rr++) {                        \
      float p1 = 0.f, p2 = 0.f;                                               \
      _Pragma("unroll") for (int nf = 0; nf < 8; nf++) {                      \
        float v = ACC[nf][rr];                                                \
        p1 += v; p2 += v * v;                                                 \
      }                                                                       \
      p1 += __shfl_xor(p1, 1, 64); p2 += __shfl_xor(p2, 1, 64);               \
      p1 += __shfl_xor(p1, 2, 64); p2 += __shfl_xor(p2, 2, 64);               \
      p1 += __shfl_xor(p1, 4, 64); p2 += __shfl_xor(p2, 4, 64);               \
      p1 += __shfl_xor(p1, 8, 64); p2 += __shfl_xor(p2, 8, 64);               \
      if (l15 == 0) {                                                         \
        int row = wm * 16 + l4 * 4 + rr;                                      \
        red[row * 8 + wn * 2] = p1;                                           \
        red[row * 8 + wn * 2 + 1] = p2;                                       \
      }                                                                       \
    }                                                                         \
  }

#define LNAPPLY1(ACC)                                                         \
  {                                                                           \
    float muA[4], rsA[4];                                                     \
    _Pragma("unroll") for (int rr = 0; rr < 4; rr++) {                        \
      int row = wm * 16 + l4 * 4 + rr;                                        \
      float s1 = red[row * 8] + red[row * 8 + 2] + red[row * 8 + 4] + red[row * 8 + 6]; \
      float s2 = red[row * 8 + 1] + red[row * 8 + 3] + red[row * 8 + 5] + red[row * 8 + 7]; \
      float mu = s1 * (1.f / 512.f);                                          \
      float var = s2 * (1.f / 512.f) - mu * mu;                               \
      muA[rr] = mu;                                                           \
      rsA[rr] = rsqrtf(fmaxf(var, 0.f) + EPSF);                               \
    }                                                                         \
    _Pragma("unroll") for (int nf = 0; nf < 8; nf++) {                        \
      int col = wn * 128 + nf * 16 + l15;                                     \
      float gg = gbuf[col], bbv = gbuf[512 + col];                            \
      _Pragma("unroll") for (int rr = 0; rr < 4; rr++) {                      \
        int row = wm * 16 + l4 * 4 + rr;                                      \
        float y = (ACC[nf][rr] - muA[rr]) * rsA[rr] * gg + bbv;               \
        y = fsilu(y);                                                         \
        int byo = row * 1024 + ((((col >> 3) << 4) ^ ((row & 7) << 4)) | ((col & 7) << 1)); \
        Abuf[byo >> 1] = f2bf(y);                                             \
      }                                                                       \
    }                                                                         \
  }

// K=512 MFMA loop: acc2 += Abuf(64x512, swizzled) @ WT^T, Bbuf dbuf staging.
// Caller stages kt=0 into Bbuf half 0 before calling (no barrier needed).
__device__ __forceinline__ void kloop512(
    const unsigned short* __restrict__ WT, unsigned short* Abuf,
    unsigned short* Bbuf, f32x4 (&acc2)[8], int t, int wm, int wn,
    int l15, int l4) {
  for (int kt = 0; kt < 16; kt++) {
    __syncthreads();              // drains in-flight gloads (vmcnt) + LDS hazards
    int cur = kt & 1;
    if (kt < 15) {                // prefetch next K-tile into other half
#pragma unroll
      for (int i = 0; i < 2; i++) {
        int o = t * 16 + i * 16384;
        int n = o >> 6, g = (o >> 4) & 3;
        gload16(WT + (size_t)n * 512 + (kt + 1) * 32 + ((g ^ ((n >> 1) & 3)) * 8),
                (char*)Bbuf + (cur ^ 1) * 32768 + o);
      }
    }
    bf16x8 a2, bv[8];
    {
      int row = wm * 16 + l15;
      a2 = *(const bf16x8*)(const void*)
          &Abuf[(row * 1024 + (((kt * 4 + l4) ^ (row & 7)) << 4)) >> 1];
    }
#pragma unroll
    for (int nf = 0; nf < 8; nf++) {
      int n = wn * 128 + nf * 16 + l15;
      bv[nf] = *(const bf16x8*)(const void*)
          &Bbuf[cur * 16384 + n * 32 + ((l4 ^ ((n >> 1) & 3)) * 8)];
    }
#pragma unroll
    for (int nf = 0; nf < 8; nf++)
      acc2[nf] = __builtin_amdgcn_mfma_f32_16x16x32_bf16(a2, bv[nf], acc2[nf], 0, 0, 0);
  }
}
// stage kt=0 of WT into Bbuf half 0 (32 KB / 1024 thr)
__device__ __forceinline__ void stage_kt0(
    const unsigned short* __restrict__ WT, unsigned short* Bbuf, int t) {
#pragma unroll
  for (int i = 0; i < 2; i++) {
    int o = t * 16 + i * 16384;
    int n = o >> 6, g = (o >> 4) & 3;
    gload16(WT + (size_t)n * 512 + ((g ^ ((n >> 1) & 3)) * 8), (char*)Bbuf + o);
  }
}

// ---------- fused value tail: hv @ W1 -> LN/silu -> @ W2 -> LN/silu -> head --
// grid (32), 1024 thr = 16 waves (4M x 4N), block = 64 rows x 512 cols.
// Replaces 2x gemm_abt + 2x ln_silu (+CF f32 round-trips + 3 launch gaps).
__global__ __launch_bounds__(1024, 4) void v_tail(
    const unsigned short* __restrict__ hv, const unsigned short* __restrict__ W1T,
    const void* __restrict__ gam1, const void* __restrict__ bet1,
    const unsigned short* __restrict__ W2T,
    const void* __restrict__ gam2, const void* __restrict__ bet2,
    const void* __restrict__ vWh, const void* __restrict__ vbh,
    float* __restrict__ valout, const int* __restrict__ flags) {
  __shared__ __align__(16) unsigned short Abuf[64 * 512];     // 64 KB
  __shared__ __align__(16) unsigned short Bbuf[2 * 512 * 32]; // 64 KB
  __shared__ float gbuf[1024];                                // 4 KB
  __shared__ float whb[512];                                  // 2 KB
  __shared__ float red[512];                                  // 2 KB

  int t = threadIdx.x;
  int w = t >> 6, l = t & 63, l15 = l & 15, l4 = l >> 4;
  int wm = w >> 2, wn = w & 3;
  int mode = flags[0];
  int b0 = blockIdx.x * 64;

  // stage hv rows -> Abuf (linear dest, pre-swizzled source; rule #21)
#pragma unroll
  for (int i = 0; i < 4; i++) {
    int o = t * 16 + i * 16384;
    int row = o >> 10, sg = (o >> 4) & 63;
    gload16(hv + (size_t)(b0 + row) * 512 + ((sg ^ (row & 7)) * 8), (char*)Abuf + o);
  }
  stage_kt0(W1T, Bbuf, t);
  if (t < 512) {
    gbuf[t] = ldx(gam1, t, mode);
    gbuf[512 + t] = ldx(bet1, t, mode);
  }
  // GEMM 1: h1 = hv @ W1   (first kloop barrier drains Abuf+Bbuf gloads)
  f32x4 acc2[8];
#pragma unroll
  for (int nf = 0; nf < 8; nf++) acc2[nf] = (f32x4){0.f, 0.f, 0.f, 0.f};
  kloop512(W1T, Abuf, Bbuf, acc2, t, wm, wn, l15, l4);
  // LN(g1,b1)+silu -> Abuf
  LNSTATS1(acc2)
  __syncthreads();
  LNAPPLY1(acc2)
  __syncthreads();
  // GEMM 2: h2 = T1 @ W2
  stage_kt0(W2T, Bbuf, t);
#pragma unroll
  for (int nf = 0; nf < 8; nf++) acc2[nf] = (f32x4){0.f, 0.f, 0.f, 0.f};
  kloop512(W2T, Abuf, Bbuf, acc2, t, wm, wn, l15, l4);
  // LN(g2,b2)+silu + value head: valout[row] = sum_col y*wh[col] + bias
  if (t < 512) {
    gbuf[t] = ldx(gam2, t, mode);
    gbuf[512 + t] = ldx(bet2, t, mode);
    whb[t] = ldx(vWh, t, mode);
  }
  LNSTATS1(acc2)
  __syncthreads();               // red stats ready; gbuf/whb visible
  {
    float muA[4], rsA[4];
#pragma unroll
    for (int rr = 0; rr < 4; rr++) {
      int row = wm * 16 + l4 * 4 + rr;
      float s1 = red[row * 8] + red[row * 8 + 2] + red[row * 8 + 4] + red[row * 8 + 6];
      float s2 = red[row * 8 + 1] + red[row * 8 + 3] + red[row * 8 + 5] + red[row * 8 + 7];
      float mu = s1 * (1.f / 512.f);
      float var = s2 * (1.f / 512.f) - mu * mu;
      muA[rr] = mu;
      rsA[rr] = rsqrtf(fmaxf(var, 0.f) + EPSF);
    }
    float hp[4] = {0.f, 0.f, 0.f, 0.f};
#pragma unroll
    for (int nf = 0; nf < 8; nf++) {
      int col = wn * 128 + nf * 16 + l15;
      float gg = gbuf[col], bbv = gbuf[512 + col], whv = whb[col];
#pragma unroll
      for (int rr = 0; rr < 4; rr++) {
        float y = (acc2[nf][rr] - muA[rr]) * rsA[rr] * gg + bbv;
        hp[rr] += fsilu(y) * whv;
      }
    }
#pragma unroll
    for (int rr = 0; rr < 4; rr++) {
      hp[rr] += __shfl_xor(hp[rr], 1, 64);
      hp[rr] += __shfl_xor(hp[rr], 2, 64);
      hp[rr] += __shfl_xor(hp[rr], 4, 64);
      hp[rr] += __shfl_xor(hp[rr], 8, 64);
    }
    __syncthreads();             // all stat reads done before red reuse
    if (l15 == 0) {
#pragma unroll
      for (int rr = 0; rr < 4; rr++) {
        int row = wm * 16 + l4 * 4 + rr;
        red[row * 8 + wn * 2] = hp[rr];
      }
    }
    __syncthreads();
    if (t < 64) {
      float s = red[t * 8] + red[t * 8 + 2] + red[t * 8 + 4] + red[t * 8 + 6];
      valout[b0 + t] = s + ldx(vbh, 0, mode);
    }
  }
}

// ---------- fused q-tail (R8 4Mx4N + R11 fast-math; ~88 us) ------------------
__global__ __launch_bounds__(1024, 4) void q_tail(
    const float* __restrict__ base, const int* __restrict__ cat,
    const void* __restrict__ qW1, const void* __restrict__ gam1,
    const void* __restrict__ bet1, const unsigned short* __restrict__ qW2T,
    const void* __restrict__ gam2, const void* __restrict__ bet2,
    const unsigned short* __restrict__ qWhT, const void* __restrict__ qbh,
    float* __restrict__ outAdv, const int* __restrict__ flags) {
  __shared__ __align__(16) unsigned short Abuf[64 * 512];     // 64 KB
  __shared__ __align__(16) unsigned short Bbuf[2 * 512 * 32]; // 64 KB
  __shared__ __align__(16) unsigned short actb[64 * 8];       // 1 KB
  __shared__ float gbuf[1024];                                // 4 KB
  __shared__ float red[512];                                  // 2 KB

  int t = threadIdx.x;
  int w = t >> 6, l = t & 63, l15 = l & 15, l4 = l >> 4;
  int wm = w >> 2, wn = w & 3;     // 4M x 4N wave grid
  int mode = flags[0], w64 = flags[1];
  int s = blockIdx.x, ls = s >> 3, ds = s & 7;
  int b0 = blockIdx.y * 64;

  // ---- stage: act (bf16), WpT = qW1[512:520]^T zero-padded to K=32, g1/b1
  if (t < 512) {
    {
      int r = t >> 3, d = t & 7;
      size_t ci = (size_t)(b0 + r) * 24 + d;
      int c0 = w64 ? cat[2 * ci] : cat[ci];
      int c1 = w64 ? cat[2 * (ci + 8)] : cat[ci + 8];
      int c2 = w64 ? cat[2 * (ci + 16)] : cat[ci + 16];
      float m1 = -1.f + (2.f * c0 + 1.f) * 0.0625f;
      float m2 = m1 - 0.0625f + (2.f * c1 + 1.f) * 0.00390625f;
      float m3 = m2 - 0.00390625f + (2.f * c2 + 1.f) * 0.000244140625f;
      int lv = ls + ((d < ds) ? 1 : 0);
      float av = (lv == 0) ? 0.f : ((lv == 1) ? m1 : ((lv == 2) ? m2 : m3));
      actb[r * 8 + d] = f2bf(av);
    }
    {
      svec8 wv, z = {};
#pragma unroll
      for (int d = 0; d < 8; d++)
        wv[d] = (short)f2bf(ldx(qW1, (size_t)(512 + d) * 512 + t, mode));
      int n = t, key = (n >> 1) & 3;
      *(svec8*)&Bbuf[n * 32 + (0 ^ key) * 8] = wv;
      *(svec8*)&Bbuf[n * 32 + (1 ^ key) * 8] = z;
      *(svec8*)&Bbuf[n * 32 + (2 ^ key) * 8] = z;
      *(svec8*)&Bbuf[n * 32 + (3 ^ key) * 8] = z;
    }
    gbuf[t] = ldx(gam1, t, mode);
    gbuf[512 + t] = ldx(bet1, t, mode);
  }
  __syncthreads();

  // ---- phase 1: acc = base + act @ Wp  (MFMA, K=32 zero-padded)
  f32x4 acc[8];
#pragma unroll
  for (int nf = 0; nf < 8; nf++) {
    int col = wn * 128 + nf * 16 + l15;
#pragma unroll
    for (int rr = 0; rr < 4; rr++) {
      int row = b0 + wm * 16 + l4 * 4 + rr;
      acc[nf][rr] = base[(size_t)row * 512 + col];
    }
  }
  {
    bf16x8 af;
    if (l4 == 0) {
      af = *(const bf16x8*)(const void*)&actb[(wm * 16 + l15) * 8];
    } else {
      svec8 z = {};
      af = __builtin_bit_cast(bf16x8, z);
    }
#pragma unroll
    for (int nf = 0; nf < 8; nf++) {
      int n = wn * 128 + nf * 16 + l15;
      bf16x8 bfv = *(const bf16x8*)(const void*)
          &Bbuf[n * 32 + ((l4 ^ ((n >> 1) & 3)) * 8)];
      acc[nf] = __builtin_amdgcn_mfma_f32_16x16x32_bf16(af, bfv, acc[nf], 0, 0, 0);
    }
  }
  // LN + silu -> hq1 into Abuf (swizzled bf16)
  LNSTATS1(acc)
  __syncthreads();
  LNAPPLY1(acc)
  __syncthreads();

  // ---- phase 2: acc2 = hq1 @ qW2 (B from qW2T, double-buffered gload staging)
  f32x4 acc2[8];
#pragma unroll
  for (int nf = 0; nf < 8; nf++) acc2[nf] = (f32x4){0.f, 0.f, 0.f, 0.f};
  stage_kt0(qW2T, Bbuf, t);
  kloop512(qW2T, Abuf, Bbuf, acc2, t, wm, wn, l15, l4);
  __syncthreads();

  // ---- phase 3: LN(g2,b2)+silu on acc2 -> Y (Abuf); adv = Y @ qWhT[s-slice]
  {                               // stage Wh slice [16][512] into Bbuf half 0
    int o = t * 16;               // 16 KB / 1024 thr = 1 load
    int rw = o >> 10, G = (o >> 4) & 63;
    gload16(qWhT + (size_t)(s * 16 + rw) * 512 + ((G ^ (rw & 7)) * 8), (char*)Bbuf + o);
  }
  if (t < 512) {
    gbuf[t] = ldx(gam2, t, mode);
    gbuf[512 + t] = ldx(bet2, t, mode);
  }
  LNSTATS1(acc2)
  __syncthreads();
  LNAPPLY1(acc2)
  __syncthreads();

  if (w < 4) {
    f32x4 a4 = {0.f, 0.f, 0.f, 0.f};
    int row = w * 16 + l15;
    int rw = l15;
#pragma unroll
    for (int kt = 0; kt < 16; kt++) {
      bf16x8 ya = *(const bf16x8*)(const void*)
          &Abuf[(row * 1024 + (((kt * 4 + l4) ^ (row & 7)) << 4)) >> 1];
      bf16x8 wb = *(const bf16x8*)(const void*)
          &Bbuf[rw * 512 + (((kt * 4 + l4) ^ (rw & 7)) * 8)];
      a4 = __builtin_amdgcn_mfma_f32_16x16x32_bf16(ya, wb, a4, 0, 0, 0);
    }
    float qb = ldx(qbh, s * 16 + l15, mode);
#pragma unroll
    for (int rr = 0; rr < 4; rr++) {
      int b = b0 + w * 16 + l4 * 4 + rr;
      outAdv[(size_t)b * 384 + s * 16 + l15] = a4[rr] + qb;
    }
  }
}

extern "C" void kernel_launch(void* const* d_in, const int* in_sizes, int n_in,
                              void* d_out, int out_size, void* d_ws, size_t ws_size,
                              hipStream_t stream) {
  const void* rgb = d_in[0];
  const void* low = d_in[1];
  const int*  cat = (const int*)d_in[2];
  float* out = (float*)d_out;   // reference output dtype is float32
  char* ws = (char*)d_ws;
  (void)in_sizes; (void)n_in; (void)out_size; (void)ws_size;

  // ---- ws layout (bytes), total 8,392,704 ------------------------------------
  int*            FLAGS = (int*)(ws + 0);                     // 4 KB
  float*          CF    = (float*)(ws + 4096);                // 2048x512 f32, 4 MB
  unsigned short* HVT1  = (unsigned short*)(ws + 4198400);    // 2 MB: hv, then QWHT
  unsigned short* WTB   = (unsigned short*)(ws + 6295552);    // 2 MB: 4 BT weights
  unsigned short* W1T   = WTB;                   // v_W1^T   512x512 bf16
  unsigned short* W2T   = WTB + 262144;          // v_W2^T
  unsigned short* QW1BT = WTB + 524288;          // q_W1[0:512]^T
  unsigned short* QW2T  = WTB + 786432;          // q_W2^T
  unsigned short* QWHT  = HVT1;                  // qWh^T (after HVT1's last use!)
  // hq lives in the adv region of d_out: last read (gemm_abt) precedes the
  // q_tail adv writes in stream order. NOTE: qWh^T must NOT live in d_out —
  // q_tail reads it while writing adv (cross-block WAR race, R4's NaN bug).
  unsigned short* HQS   = (unsigned short*)(out + 2048);      // 2 MB

  detect_mode<<<1, 256, 0, stream>>>((const unsigned short*)rgb, cat, FLAGS);

  // weight transposes into WTB (region untouched until consumed)
  tr_bf16<<<dim3(16, 16), 256, 0, stream>>>(d_in[9], 512, 512, W1T, FLAGS);
  tr_bf16<<<dim3(16, 16), 256, 0, stream>>>(d_in[12], 512, 512, W2T, FLAGS);
  tr_bf16<<<dim3(16, 16), 256, 0, stream>>>(d_in[23], 512, 512, QW1BT, FLAGS);
  tr_bf16<<<dim3(16, 16), 256, 0, stream>>>(d_in[26], 512, 512, QW2T, FLAGS);

  // rgb GEMM, split-K=8: CF += rgb @ [v_W_rgb | q_W_rgb]
  zerof<<<1024, 256, 0, stream>>>(CF, 262144);
  gemm64m<<<dim3(32, 8, 8), 256, 0, stream>>>(rgb, 8192, d_in[3], d_in[17], 256, 256,
                                              CF, 512, 1024, FLAGS, 1, 1);
  ln_heads<<<2048, 256, 0, stream>>>(CF, low, d_in[6], d_in[20],
                                     d_in[4], d_in[5], d_in[18], d_in[19],
                                     d_in[7], d_in[8], d_in[21], d_in[22],
                                     HVT1, HQS, FLAGS);
  // fused value path: hv @ W1 -> LN/silu -> @ W2 -> LN/silu -> value head
  v_tail<<<32, 1024, 0, stream>>>(HVT1, W1T, d_in[10], d_in[11], W2T,
                                  d_in[13], d_in[14], d_in[15], d_in[16],
                                  out, FLAGS);
  // HVT1 now dead -> safe to host qWh^T there (ws, not d_out)
  tr_bf16<<<dim3(16, 12), 256, 0, stream>>>(d_in[29], 512, 384, QWHT, FLAGS);
  // q path base: CF = hq @ q_W1[0:512,:]
  gemm_abt<<<dim3(32, 16), 256, 0, stream>>>(HQS, QW1BT, CF);
  // fused q tail: hq1-build + GEMM(qW2) + LN/silu + adv head, one launch
  q_tail<<<dim3(24, 32), 1024, 0, stream>>>(CF, cat, d_in[23], d_in[24], d_in[25],
                                            QW2T, d_in[27], d_in[28], QWHT, d_in[30],
                                            out + 2048, FLAGS);
}

// Round 14
// 394.371 us; speedup vs baseline: 1.0142x; 1.0142x over previous
//
#include <hip/hip_runtime.h>
#include <hip/hip_bf16.h>

#define EPSF 1e-5f

typedef __bf16 bf16x8 __attribute__((ext_vector_type(8)));
typedef float f32x4 __attribute__((ext_vector_type(4)));
typedef short svec8 __attribute__((ext_vector_type(8)));
typedef short svec4 __attribute__((ext_vector_type(4)));

__device__ __forceinline__ float bf2f(unsigned short h) {
  unsigned int u = ((unsigned int)h) << 16;
  return __builtin_bit_cast(float, u);
}
__device__ __forceinline__ unsigned short f2bf(float f) {
  unsigned int u = __builtin_bit_cast(unsigned int, f);
  unsigned int r = (u + 0x7fffu + ((u >> 16) & 1u)) >> 16;
  return (unsigned short)r;
}
// dual-mode scalar read: f32 (mode=1) or bf16 (mode=0)
__device__ __forceinline__ float ldx(const void* p, size_t i, int f32m) {
  return f32m ? ((const float*)p)[i] : bf2f(((const unsigned short*)p)[i]);
}
// dual-mode 8-element load -> 8 bf16 (svec8)
__device__ __forceinline__ svec8 ld8bf(const void* p, size_t eoff, int f32m) {
  if (!f32m) {
    uint4 u = *(const uint4*)((const unsigned short*)p + eoff);
    return __builtin_bit_cast(svec8, u);
  }
  const float* q = (const float*)p + eoff;
  float4 a = ((const float4*)q)[0];
  float4 b = ((const float4*)q)[1];
  svec8 r;
  r[0] = (short)f2bf(a.x); r[1] = (short)f2bf(a.y);
  r[2] = (short)f2bf(a.z); r[3] = (short)f2bf(a.w);
  r[4] = (short)f2bf(b.x); r[5] = (short)f2bf(b.y);
  r[6] = (short)f2bf(b.z); r[7] = (short)f2bf(b.w);
  return r;
}
// async global->LDS, 16 bytes per lane (dest must be wave-uniform base + lane*16)
__device__ __forceinline__ void gload16(const void* g, void* l) {
  __builtin_amdgcn_global_load_lds(
      (const __attribute__((address_space(1))) unsigned int*)g,
      (__attribute__((address_space(3))) unsigned int*)l, 16, 0, 0);
}
// fast silu: y * 1/(1+e^-y) via native exp (err ~1e-6 << bf16 rounding)
__device__ __forceinline__ float fsilu(float y) {
  return y * __builtin_amdgcn_rcpf(1.f + __expf(-y));
}
// fast tanh: 1 - 2/(e^{2y}+1); exact limits at +/-inf
__device__ __forceinline__ float ftanh(float y) {
  return 1.f - 2.f * __builtin_amdgcn_rcpf(__expf(2.f * y) + 1.f);
}

// block-wide (256 thr) sum of (x,y) via wave shuffles; s = float[16] scratch
__device__ __forceinline__ float2 bred2(float x, float y, float* s) {
#pragma unroll
  for (int o = 32; o > 0; o >>= 1) {
    x += __shfl_xor(x, o, 64);
    y += __shfl_xor(y, o, 64);
  }
  int w = threadIdx.x >> 6;
  if ((threadIdx.x & 63) == 0) { s[w] = x; s[8 + w] = y; }
  __syncthreads();
  float rx = s[0] + s[1] + s[2] + s[3];
  float ry = s[8] + s[9] + s[10] + s[11];
  __syncthreads();
  return make_float2(rx, ry);
}

// ---- probes: flags[0]=1 if float inputs are f32; flags[1]=1 if cat is int64
__global__ void detect_mode(const unsigned short* rgb, const int* cat, int* flags) {
  __shared__ int c1s, c2s;
  if (threadIdx.x == 0) { c1s = 0; c2s = 0; }
  __syncthreads();
  int c1 = 0, c2 = 0;
  for (int i = threadIdx.x; i < 4096; i += 256) {
    unsigned e = (rgb[i] >> 7) & 0xFFu;
    if (e >= 0x90u) c1++;
  }
  for (int i = threadIdx.x; i < 1024; i += 256) {
    if (cat[2 * i + 1] != 0) c2++;
  }
  atomicAdd(&c1s, c1);
  atomicAdd(&c2s, c2);
  __syncthreads();
  if (threadIdx.x == 0) {
    flags[0] = (c1s > 64) ? 1 : 0;
    flags[1] = (c2s < 8) ? 1 : 0;
  }
}

// ---- zero an f32 buffer (graph-safe, re-run every launch) -------------------
__global__ void zerof(float* p, int n4) {
  int i = blockIdx.x * 256 + threadIdx.x;
  if (i < n4) ((float4*)p)[i] = make_float4(0.f, 0.f, 0.f, 0.f);
}

// -------- MFMA GEMM, natural-layout B (rgb path; R11-measured 92 us) ---------
__global__ __launch_bounds__(256) void gemm64m(
    const void* __restrict__ A, int lda,
    const void* __restrict__ B0, const void* __restrict__ B1,
    int ldbn, int nsplit,
    void* __restrict__ Cv, int ldc, int kslice,
    const int* __restrict__ flags, int aDyn, int outKind) {
  __shared__ __align__(16) unsigned short As[64 * 40];
  __shared__ __align__(16) unsigned short Bs[32 * 68];
  int t = threadIdx.x;
  int mode = flags[0], am = aDyn ? mode : 0;
  int wave = t >> 6, lane = t & 63, mr = lane & 15, q = lane >> 4;
  int m0 = blockIdx.x * 64, n0 = blockIdx.y * 64;
  int kbeg = blockIdx.z * kslice;
  const void* B = B0; int nb = n0;
  if (n0 >= nsplit) { B = B1; nb = n0 - nsplit; }
  int arow = t >> 2, acol = (t & 3) * 8;   // A-tile 64m x 32k
  int brow = t >> 3, bcol = (t & 7) * 8;   // B-tile 32k x 64n
  size_t abase = (size_t)(m0 + arow) * lda + kbeg + acol;
  size_t bbase = (size_t)(kbeg + brow) * ldbn + nb + bcol;
  f32x4 acc[4];
#pragma unroll
  for (int i = 0; i < 4; i++) acc[i] = (f32x4){0.f, 0.f, 0.f, 0.f};
  svec8 ra = ld8bf(A, abase, am);
  svec8 rb = ld8bf(B, bbase, mode);
  int aw = arow * 40 + acol;
  int bw = brow * 68 + bcol;
  for (int k0 = 0; k0 < kslice; k0 += 32) {
    *(svec8*)&As[aw] = ra;
    *(svec4*)&Bs[bw]     = __builtin_shufflevector(rb, rb, 0, 1, 2, 3);
    *(svec4*)&Bs[bw + 4] = __builtin_shufflevector(rb, rb, 4, 5, 6, 7);
    __syncthreads();
    if (k0 + 32 < kslice) {  // register prefetch of next K-tile
      ra = ld8bf(A, abase + k0 + 32, am);
      rb = ld8bf(B, bbase + (size_t)(k0 + 32) * ldbn, mode);
    }
    svec8 bsv;
#pragma unroll
    for (int j = 0; j < 8; j++)
      bsv[j] = (short)Bs[(q * 8 + j) * 68 + wave * 16 + mr];
    bf16x8 bfr = __builtin_bit_cast(bf16x8, bsv);
#pragma unroll
    for (int i = 0; i < 4; i++) {
      bf16x8 afr = *(const bf16x8*)(const void*)&As[(i * 16 + mr) * 40 + q * 8];
      acc[i] = __builtin_amdgcn_mfma_f32_16x16x32_bf16(afr, bfr, acc[i], 0, 0, 0);
    }
    __syncthreads();
  }
  int n = n0 + wave * 16 + mr;
  if (outKind == 2) {
    unsigned short* C = (unsigned short*)Cv;
#pragma unroll
    for (int i = 0; i < 4; i++)
#pragma unroll
      for (int r = 0; r < 4; r++)
        C[(size_t)(m0 + i * 16 + q * 4 + r) * ldc + n] = f2bf(acc[i][r]);
  } else if (outKind == 0) {
    float* C = (float*)Cv;
#pragma unroll
    for (int i = 0; i < 4; i++)
#pragma unroll
      for (int r = 0; r < 4; r++)
        C[(size_t)(m0 + i * 16 + q * 4 + r) * ldc + n] = acc[i][r];
  } else {
    float* C = (float*)Cv;
#pragma unroll
    for (int i = 0; i < 4; i++)
#pragma unroll
      for (int r = 0; r < 4; r++)
        atomicAdd(&C[(size_t)(m0 + i * 16 + q * 4 + r) * ldc + n], acc[i][r]);
  }
}

// -------- LDS-free GEMM: C[2048,512] f32 = A[2048,512]bf16 @ BT[512,512]^T ---
// grid (32, 16): block = 4 independent waves, wave = 16 rows x 32 cols.
__global__ __launch_bounds__(256) void gemm_abt(
    const unsigned short* __restrict__ A, const unsigned short* __restrict__ BT,
    float* __restrict__ C) {
  int t = threadIdx.x;
  int w = t >> 6, l = t & 63, l15 = l & 15, l4 = l >> 4;
  int r0 = (blockIdx.x * 4 + w) * 16;
  int c0 = blockIdx.y * 32;
  f32x4 acc0 = (f32x4){0.f, 0.f, 0.f, 0.f}, acc1 = acc0;
  const unsigned short* Ap  = A  + (size_t)(r0 + l15) * 512 + l4 * 8;
  const unsigned short* Bp0 = BT + (size_t)(c0 + l15) * 512 + l4 * 8;
  const unsigned short* Bp1 = Bp0 + 16 * 512;
#pragma unroll 4
  for (int k0 = 0; k0 < 512; k0 += 32) {
    bf16x8 af = *(const bf16x8*)(const void*)(Ap + k0);
    bf16x8 b0 = *(const bf16x8*)(const void*)(Bp0 + k0);
    bf16x8 b1 = *(const bf16x8*)(const void*)(Bp1 + k0);
    acc0 = __builtin_amdgcn_mfma_f32_16x16x32_bf16(af, b0, acc0, 0, 0, 0);
    acc1 = __builtin_amdgcn_mfma_f32_16x16x32_bf16(af, b1, acc1, 0, 0, 0);
  }
#pragma unroll
  for (int rr = 0; rr < 4; rr++) {
    C[(size_t)(r0 + l4 * 4 + rr) * 512 + c0 + l15] = acc0[rr];
    C[(size_t)(r0 + l4 * 4 + rr) * 512 + c0 + 16 + l15] = acc1[rr];
  }
}

// --------- heads: LN(rgb GEMM halves)+tanh + tiny low-obs path ---------------
// R14: all 8 reduction quantities (4 sums + 4 sumsq) reduced in ONE
// interleaved shuffle pass + ONE barrier (was 4x bred2 = 8 barriers).
__global__ __launch_bounds__(256) void ln_heads(
    const float* __restrict__ CF, const void* __restrict__ low,
    const void* __restrict__ vWlow, const void* __restrict__ qWlow,
    const void* __restrict__ vgr, const void* __restrict__ vbr,
    const void* __restrict__ qgr, const void* __restrict__ qbr,
    const void* __restrict__ vgl, const void* __restrict__ vbl,
    const void* __restrict__ qgl, const void* __restrict__ qbl,
    unsigned short* __restrict__ hv, unsigned short* __restrict__ hq,
    const int* __restrict__ flags) {
  __shared__ float lowf[32];
  __shared__ float red8[32];   // 4 waves x 8 quantities
  int mode = flags[0];
  int b = blockIdx.x, j = threadIdx.x;
  if (j < 32) lowf[j] = ldx(low, (size_t)b * 32 + j, mode);
  __syncthreads();
  float xvr = CF[(size_t)b * 512 + j];
  float xqr = CF[(size_t)b * 512 + 256 + j];
  float xvl = 0.f, xql = 0.f;
#pragma unroll 4
  for (int k = 0; k < 32; k++) {
    float l = lowf[k];
    xvl += l * ldx(vWlow, k * 256 + j, mode);
    xql += l * ldx(qWlow, k * 256 + j, mode);
  }
  float v[8] = {xvr, xvr * xvr, xvl, xvl * xvl, xqr, xqr * xqr, xql, xql * xql};
#pragma unroll
  for (int o = 32; o > 0; o >>= 1)
#pragma unroll
    for (int i = 0; i < 8; i++) v[i] += __shfl_xor(v[i], o, 64);
  int wv = j >> 6;
  if ((j & 63) == 0)
#pragma unroll
    for (int i = 0; i < 8; i++) red8[wv * 8 + i] = v[i];
  __syncthreads();
  float s[8];
#pragma unroll
  for (int i = 0; i < 8; i++)
    s[i] = red8[i] + red8[8 + i] + red8[16 + i] + red8[24 + i];
  {
    float mu = s[0] * (1.f / 256.f), var = s[1] * (1.f / 256.f) - mu * mu;
    float y = (xvr - mu) * rsqrtf(fmaxf(var, 0.f) + EPSF) * ldx(vgr, j, mode) + ldx(vbr, j, mode);
    hv[(size_t)b * 512 + j] = f2bf(ftanh(y));
  }
  {
    float mu = s[2] * (1.f / 256.f), var = s[3] * (1.f / 256.f) - mu * mu;
    float y = (xvl - mu) * rsqrtf(fmaxf(var, 0.f) + EPSF) * ldx(vgl, j, mode) + ldx(vbl, j, mode);
    hv[(size_t)b * 512 + 256 + j] = f2bf(ftanh(y));
  }
  {
    float mu = s[4] * (1.f / 256.f), var = s[5] * (1.f / 256.f) - mu * mu;
    float y = (xqr - mu) * rsqrtf(fmaxf(var, 0.f) + EPSF) * ldx(qgr, j, mode) + ldx(qbr, j, mode);
    hq[(size_t)b * 512 + j] = f2bf(ftanh(y));
  }
  {
    float mu = s[6] * (1.f / 256.f), var = s[7] * (1.f / 256.f) - mu * mu;
    float y = (xql - mu) * rsqrtf(fmaxf(var, 0.f) + EPSF) * ldx(qgl, j, mode) + ldx(qbl, j, mode);
    hq[(size_t)b * 512 + 256 + j] = f2bf(ftanh(y));
  }
}

// ---------- LN(512)+silu; optional store (outh) and fused value head ---------
__global__ __launch_bounds__(256) void ln_silu(
    const float* __restrict__ CF, const void* __restrict__ g,
    const void* __restrict__ bb, unsigned short* __restrict__ outh,
    const void* __restrict__ Wh, const void* __restrict__ bh,
    float* __restrict__ valout, const int* __restrict__ flags) {
  __shared__ float red[16];
  int mode = flags[0];
  int b = blockIdx.x, j = threadIdx.x;
  float x0 = CF[(size_t)b * 512 + j];
  float x1 = CF[(size_t)b * 512 + 256 + j];
  float2 r = bred2(x0 + x1, x0 * x0 + x1 * x1, red);
  float mu = r.x * (1.f / 512.f);
  float var = r.y * (1.f / 512.f) - mu * mu;
  float rs = rsqrtf(fmaxf(var, 0.f) + EPSF);
  float y0 = (x0 - mu) * rs * ldx(g, j, mode) + ldx(bb, j, mode);
  float y1 = (x1 - mu) * rs * ldx(g, j + 256, mode) + ldx(bb, j + 256, mode);
  y0 = fsilu(y0);
  y1 = fsilu(y1);
  if (outh != nullptr) {
    outh[(size_t)b * 512 + j] = f2bf(y0);
    outh[(size_t)b * 512 + 256 + j] = f2bf(y1);
  }
  if (Wh != nullptr) {
    float p = y0 * ldx(Wh, j, mode) + y1 * ldx(Wh, j + 256, mode);
    float2 rv = bred2(p, 0.f, red);
    if (j == 0) valout[b] = rv.x + ldx(bh, 0, mode);
  }
}

// ---------- transpose natural [K][N] (f32 or bf16) -> bf16 out[N][K] ---------
__global__ __launch_bounds__(256) void tr_bf16(
    const void* __restrict__ in, int K, int N,
    unsigned short* __restrict__ out, const int* __restrict__ flags) {
  __shared__ float tile[32][33];
  int mode = flags[0];
  int k0 = blockIdx.x * 32, n0 = blockIdx.y * 32;
  int t = threadIdx.x, ty = t >> 5, tx = t & 31;
#pragma unroll
  for (int i = 0; i < 4; i++)
    tile[ty + i * 8][tx] = ldx(in, (size_t)(k0 + ty + i * 8) * N + n0 + tx, mode);
  __syncthreads();
#pragma unroll
  for (int i = 0; i < 4; i++)
    out[(size_t)(n0 + ty + i * 8) * K + k0 + tx] = f2bf(tile[tx][ty + i * 8]);
}

// ---------- fused q-tail (R12-measured inline form, ~101.5 us; the helper-fn
// refactor of R13 spilled ~20 MB scratch — keep THIS exact source shape) -----
#define LNSTATS1(ACC)                                                         \
  {                                                                           \
    _Pragma("unroll") for (int rr = 0; rr < 4; rr++) {                        \
      float p1 = 0.f, p2 = 0.f;                                               \
      _Pragma("unroll") for (int nf = 0; nf < 8; nf++) {                      \
        float v = ACC[nf][rr];                                                \
        p1 += v; p2 += v * v;                                                 \
      }                                                                       \
      p1 += __shfl_xor(p1, 1, 64); p2 += __shfl_xor(p2, 1, 64);               \
      p1 += __shfl_xor(p1, 2, 64); p2 += __shfl_xor(p2, 2, 64);               \
      p1 += __shfl_xor(p1, 4, 64); p2 += __shfl_xor(p2, 4, 64);               \
      p1 += __shfl_xor(p1, 8, 64); p2 += __shfl_xor(p2, 8, 64);               \
      if (l15 == 0) {                                                         \
        int row = wm * 16 + l4 * 4 + rr;                                      \
        red[row * 8 + wn * 2] = p1;                                           \
        red[row * 8 + wn * 2 + 1] = p2;                                       \
      }                                                                       \
    }                                                                         \
  }

#define LNAPPLY1(ACC)                                                         \
  {                                                                           \
    float muA[4], rsA[4];                                                     \
    _Pragma("unroll") for (int rr = 0; rr < 4; rr++) {                        \
      int row = wm * 16 + l4 * 4 + rr;                                        \
      float s1 = red[row * 8] + red[row * 8 + 2] + red[row * 8 + 4] + red[row * 8 + 6]; \
      float s2 = red[row * 8 + 1] + red[row * 8 + 3] + red[row * 8 + 5] + red[row * 8 + 7]; \
      float mu = s1 * (1.f / 512.f);                                          \
      float var = s2 * (1.f / 512.f) - mu * mu;                               \
      muA[rr] = mu;                                                           \
      rsA[rr] = rsqrtf(fmaxf(var, 0.f) + EPSF);                               \
    }                                                                         \
    _Pragma("unroll") for (int nf = 0; nf < 8; nf++) {                        \
      int col = wn * 128 + nf * 16 + l15;                                     \
      float gg = gbuf[col], bbv = gbuf[512 + col];                            \
      _Pragma("unroll") for (int rr = 0; rr < 4; rr++) {                      \
        int row = wm * 16 + l4 * 4 + rr;                                      \
        float y = (ACC[nf][rr] - muA[rr]) * rsA[rr] * gg + bbv;               \
        y = fsilu(y);                                                         \
        int byo = row * 1024 + ((((col >> 3) << 4) ^ ((row & 7) << 4)) | ((col & 7) << 1)); \
        Abuf[byo >> 1] = f2bf(y);                                             \
      }                                                                       \
    }                                                                         \
  }

__global__ __launch_bounds__(1024, 4) void q_tail(
    const float* __restrict__ base, const int* __restrict__ cat,
    const void* __restrict__ qW1, const void* __restrict__ gam1,
    const void* __restrict__ bet1, const unsigned short* __restrict__ qW2T,
    const void* __restrict__ gam2, const void* __restrict__ bet2,
    const unsigned short* __restrict__ qWhT, const void* __restrict__ qbh,
    float* __restrict__ outAdv, const int* __restrict__ flags) {
  __shared__ __align__(16) unsigned short Abuf[64 * 512];     // 64 KB
  __shared__ __align__(16) unsigned short Bbuf[2 * 512 * 32]; // 64 KB
  __shared__ __align__(16) unsigned short actb[64 * 8];       // 1 KB
  __shared__ float gbuf[1024];                                // 4 KB
  __shared__ float red[512];                                  // 2 KB

  int t = threadIdx.x;
  int w = t >> 6, l = t & 63, l15 = l & 15, l4 = l >> 4;
  int wm = w >> 2, wn = w & 3;     // 4M x 4N wave grid
  int mode = flags[0], w64 = flags[1];
  int s = blockIdx.x, ls = s >> 3, ds = s & 7;
  int b0 = blockIdx.y * 64;

  // ---- stage: act (bf16), WpT = qW1[512:520]^T zero-padded to K=32, g1/b1
  if (t < 512) {
    {
      int r = t >> 3, d = t & 7;
      size_t ci = (size_t)(b0 + r) * 24 + d;
      int c0 = w64 ? cat[2 * ci] : cat[ci];
      int c1 = w64 ? cat[2 * (ci + 8)] : cat[ci + 8];
      int c2 = w64 ? cat[2 * (ci + 16)] : cat[ci + 16];
      float m1 = -1.f + (2.f * c0 + 1.f) * 0.0625f;
      float m2 = m1 - 0.0625f + (2.f * c1 + 1.f) * 0.00390625f;
      float m3 = m2 - 0.00390625f + (2.f * c2 + 1.f) * 0.000244140625f;
      int lv = ls + ((d < ds) ? 1 : 0);
      float av = (lv == 0) ? 0.f : ((lv == 1) ? m1 : ((lv == 2) ? m2 : m3));
      actb[r * 8 + d] = f2bf(av);
    }
    {
      svec8 wv, z = {};
#pragma unroll
      for (int d = 0; d < 8; d++)
        wv[d] = (short)f2bf(ldx(qW1, (size_t)(512 + d) * 512 + t, mode));
      int n = t, key = (n >> 1) & 3;
      *(svec8*)&Bbuf[n * 32 + (0 ^ key) * 8] = wv;
      *(svec8*)&Bbuf[n * 32 + (1 ^ key) * 8] = z;
      *(svec8*)&Bbuf[n * 32 + (2 ^ key) * 8] = z;
      *(svec8*)&Bbuf[n * 32 + (3 ^ key) * 8] = z;
    }
    gbuf[t] = ldx(gam1, t, mode);
    gbuf[512 + t] = ldx(bet1, t, mode);
  }
  __syncthreads();

  // ---- phase 1: acc = base + act @ Wp  (MFMA, K=32 zero-padded)
  f32x4 acc[8];
#pragma unroll
  for (int nf = 0; nf < 8; nf++) {
    int col = wn * 128 + nf * 16 + l15;
#pragma unroll
    for (int rr = 0; rr < 4; rr++) {
      int row = b0 + wm * 16 + l4 * 4 + rr;
      acc[nf][rr] = base[(size_t)row * 512 + col];
    }
  }
  {
    bf16x8 af;
    if (l4 == 0) {
      af = *(const bf16x8*)(const void*)&actb[(wm * 16 + l15) * 8];
    } else {
      svec8 z = {};
      af = __builtin_bit_cast(bf16x8, z);
    }
#pragma unroll
    for (int nf = 0; nf < 8; nf++) {
      int n = wn * 128 + nf * 16 + l15;
      bf16x8 bfv = *(const bf16x8*)(const void*)
          &Bbuf[n * 32 + ((l4 ^ ((n >> 1) & 3)) * 8)];
      acc[nf] = __builtin_amdgcn_mfma_f32_16x16x32_bf16(af, bfv, acc[nf], 0, 0, 0);
    }
  }
  // LN + silu -> hq1 into Abuf (swizzled bf16)
  LNSTATS1(acc)
  __syncthreads();
  LNAPPLY1(acc)
  __syncthreads();

  // ---- phase 2: acc2 = hq1 @ qW2 (B from qW2T, double-buffered gload staging)
  f32x4 acc2[8];
#pragma unroll
  for (int nf = 0; nf < 8; nf++) acc2[nf] = (f32x4){0.f, 0.f, 0.f, 0.f};

#pragma unroll
  for (int i = 0; i < 2; i++) {   // stage kt=0 into half 0 (32 KB / 1024 thr)
    int o = t * 16 + i * 16384;
    int n = o >> 6, g = (o >> 4) & 3;
    gload16(qW2T + (size_t)n * 512 + ((g ^ ((n >> 1) & 3)) * 8), (char*)Bbuf + o);
  }
  for (int kt = 0; kt < 16; kt++) {
    __syncthreads();              // drains in-flight gloads (vmcnt) + LDS hazards
    int cur = kt & 1;
    if (kt < 15) {                // prefetch next K-tile into other half
#pragma unroll
      for (int i = 0; i < 2; i++) {
        int o = t * 16 + i * 16384;
        int n = o >> 6, g = (o >> 4) & 3;
        gload16(qW2T + (size_t)n * 512 + (kt + 1) * 32 + ((g ^ ((n >> 1) & 3)) * 8),
                (char*)Bbuf + (cur ^ 1) * 32768 + o);
      }
    }
    bf16x8 a2, bv[8];
    {
      int row = wm * 16 + l15;
      a2 = *(const bf16x8*)(const void*)
          &Abuf[(row * 1024 + (((kt * 4 + l4) ^ (row & 7)) << 4)) >> 1];
    }
#pragma unroll
    for (int nf = 0; nf < 8; nf++) {
      int n = wn * 128 + nf * 16 + l15;
      bv[nf] = *(const bf16x8*)(const void*)
          &Bbuf[cur * 16384 + n * 32 + ((l4 ^ ((n >> 1) & 3)) * 8)];
    }
#pragma unroll
    for (int nf = 0; nf < 8; nf++)
      acc2[nf] = __builtin_amdgcn_mfma_f32_16x16x32_bf16(a2, bv[nf], acc2[nf], 0, 0, 0);
  }
  __syncthreads();

  // ---- phase 3: LN(g2,b2)+silu on acc2 -> Y (Abuf); adv = Y @ qWhT[s-slice]
  {                               // stage Wh slice [16][512] into Bbuf half 0
    int o = t * 16;               // 16 KB / 1024 thr = 1 load
    int rw = o >> 10, G = (o >> 4) & 63;
    gload16(qWhT + (size_t)(s * 16 + rw) * 512 + ((G ^ (rw & 7)) * 8), (char*)Bbuf + o);
  }
  if (t < 512) {
    gbuf[t] = ldx(gam2, t, mode);
    gbuf[512 + t] = ldx(bet2, t, mode);
  }
  LNSTATS1(acc2)
  __syncthreads();
  LNAPPLY1(acc2)
  __syncthreads();

  if (w < 4) {
    f32x4 a4 = {0.f, 0.f, 0.f, 0.f};
    int row = w * 16 + l15;
    int rw = l15;
#pragma unroll
    for (int kt = 0; kt < 16; kt++) {
      bf16x8 ya = *(const bf16x8*)(const void*)
          &Abuf[(row * 1024 + (((kt * 4 + l4) ^ (row & 7)) << 4)) >> 1];
      bf16x8 wb = *(const bf16x8*)(const void*)
          &Bbuf[rw * 512 + (((kt * 4 + l4) ^ (rw & 7)) * 8)];
      a4 = __builtin_amdgcn_mfma_f32_16x16x32_bf16(ya, wb, a4, 0, 0, 0);
    }
    float qb = ldx(qbh, s * 16 + l15, mode);
#pragma unroll
    for (int rr = 0; rr < 4; rr++) {
      int b = b0 + w * 16 + l4 * 4 + rr;
      outAdv[(size_t)b * 384 + s * 16 + l15] = a4[rr] + qb;
    }
  }
}

extern "C" void kernel_launch(void* const* d_in, const int* in_sizes, int n_in,
                              void* d_out, int out_size, void* d_ws, size_t ws_size,
                              hipStream_t stream) {
  const void* rgb = d_in[0];
  const void* low = d_in[1];
  const int*  cat = (const int*)d_in[2];
  float* out = (float*)d_out;   // reference output dtype is float32
  char* ws = (char*)d_ws;
  (void)in_sizes; (void)n_in; (void)out_size; (void)ws_size;

  // ---- ws layout (bytes), total 8,392,704 ------------------------------------
  int*            FLAGS = (int*)(ws + 0);                     // 4 KB
  float*          CF    = (float*)(ws + 4096);                // 2048x512 f32, 4 MB
  unsigned short* HVT1  = (unsigned short*)(ws + 4198400);    // 2 MB: hv, T1, then QWHT
  unsigned short* WTB   = (unsigned short*)(ws + 6295552);    // 2 MB: 4 BT weights
  unsigned short* W1T   = WTB;                   // v_W1^T   512x512 bf16
  unsigned short* W2T   = WTB + 262144;          // v_W2^T
  unsigned short* QW1BT = WTB + 524288;          // q_W1[0:512]^T
  unsigned short* QW2T  = WTB + 786432;          // q_W2^T
  unsigned short* QWHT  = HVT1;                  // qWh^T (after HVT1's last use!)
  // hq lives in the adv region of d_out: last read (gemm_abt) precedes the
  // q_tail adv writes in stream order. NOTE: qWh^T must NOT live in d_out —
  // q_tail reads it while writing adv (cross-block WAR race, R4's NaN bug).
  unsigned short* HQS   = (unsigned short*)(out + 2048);      // 2 MB

  detect_mode<<<1, 256, 0, stream>>>((const unsigned short*)rgb, cat, FLAGS);

  // weight transposes into WTB (region untouched until q path)
  tr_bf16<<<dim3(16, 16), 256, 0, stream>>>(d_in[9], 512, 512, W1T, FLAGS);
  tr_bf16<<<dim3(16, 16), 256, 0, stream>>>(d_in[12], 512, 512, W2T, FLAGS);
  tr_bf16<<<dim3(16, 16), 256, 0, stream>>>(d_in[23], 512, 512, QW1BT, FLAGS);
  tr_bf16<<<dim3(16, 16), 256, 0, stream>>>(d_in[26], 512, 512, QW2T, FLAGS);

  // rgb GEMM, split-K=8: CF += rgb @ [v_W_rgb | q_W_rgb]
  zerof<<<1024, 256, 0, stream>>>(CF, 262144);
  gemm64m<<<dim3(32, 8, 8), 256, 0, stream>>>(rgb, 8192, d_in[3], d_in[17], 256, 256,
                                              CF, 512, 1024, FLAGS, 1, 1);
  ln_heads<<<2048, 256, 0, stream>>>(CF, low, d_in[6], d_in[20],
                                     d_in[4], d_in[5], d_in[18], d_in[19],
                                     d_in[7], d_in[8], d_in[21], d_in[22],
                                     HVT1, HQS, FLAGS);
  // value path: hv @ v_W1 -> CF ; T1 @ v_W2 -> CF (LDS-free BT GEMMs)
  gemm_abt<<<dim3(32, 16), 256, 0, stream>>>(HVT1, W1T, CF);
  ln_silu<<<2048, 256, 0, stream>>>(CF, d_in[10], d_in[11], HVT1, nullptr, nullptr,
                                    nullptr, FLAGS);
  gemm_abt<<<dim3(32, 16), 256, 0, stream>>>(HVT1, W2T, CF);
  ln_silu<<<2048, 256, 0, stream>>>(CF, d_in[13], d_in[14], nullptr, d_in[15], d_in[16],
                                    out, FLAGS);
  // HVT1 now dead -> safe to host qWh^T there (ws, not d_out)
  tr_bf16<<<dim3(16, 12), 256, 0, stream>>>(d_in[29], 512, 384, QWHT, FLAGS);
  // q path base: CF = hq @ q_W1[0:512,:]
  gemm_abt<<<dim3(32, 16), 256, 0, stream>>>(HQS, QW1BT, CF);
  // fused q tail: hq1-build + GEMM(qW2) + LN/silu + adv head, one launch
  q_tail<<<dim3(24, 32), 1024, 0, stream>>>(CF, cat, d_in[23], d_in[24], d_in[25],
                                            QW2T, d_in[27], d_in[28], QWHT, d_in[30],
                                            out + 2048, FLAGS);
}